// Round 24
// baseline (785.857 us; speedup 1.0000x reference)
//
#include <hip/hip_runtime.h>
#include <hip/hip_bf16.h>

#define B_ 256
#define T_ 512
#define IN_ 202
#define HID_ 100
#define K_ 19

// dynamic-LDS float offsets for k_crf (2 sequences per block)
#define ES0_OFF 0
#define ES1_OFF 9728
#define TRS_OFF 19456              // 361 floats (pad 364)
#define STL_OFF 19820
#define ENL_OFF 19840
#define HL0_B   79440              // byte offsets, 16-aligned
#define HL1_B   89152
#define CRF2_LDS_B 98880           // ~96.6 KB

typedef __attribute__((ext_vector_type(8))) short short8v;
typedef __attribute__((ext_vector_type(4))) float f32x4;

__device__ __forceinline__ float rl_f(float v, int l) {
  return __int_as_float(__builtin_amdgcn_readlane(__float_as_int(v), l));
}
__device__ __forceinline__ float bcast_f(float v, int l) {
  return __int_as_float(__builtin_amdgcn_ds_bpermute(l * 4, __float_as_int(v)));
}
__device__ __forceinline__ float fast_tanh(float x) {
  float t = __expf(2.f * x);
  float r = __builtin_amdgcn_rcpf(t + 1.f);
  return fmaf(-2.f, r, 1.f);
}

// ---------------- K0: split [wf;wb] (200x202) into 3 exact bf16 planes, padded to 224x224.
__global__ __launch_bounds__(256, 1) void k_wprep(
    const float* __restrict__ wf, const float* __restrict__ wb,
    unsigned short* __restrict__ w3) {
  int idx = blockIdx.x * 256 + threadIdx.x;
  if (idx >= 224 * 224) return;
  int c = idx / 224, k = idx - (idx / 224) * 224;
  float v = 0.f;
  if (k < IN_) {
    if (c < 100) v = wf[c * IN_ + k];
    else if (c < 200) v = wb[(c - 100) * IN_ + k];
  }
  unsigned u0 = __float_as_uint(v) & 0xffff0000u;
  float r1 = v - __uint_as_float(u0);
  unsigned u1 = __float_as_uint(r1) & 0xffff0000u;
  float r2 = r1 - __uint_as_float(u1);
  w3[idx] = (unsigned short)(u0 >> 16);
  w3[50176 + idx] = (unsigned short)(u1 >> 16);
  w3[100352 + idx] = (unsigned short)(__float_as_uint(r2) >> 16);
}

// ---------------- K1: pre = x . [wf;wb]^T + bias via bf16-split MFMA (round-18 proven).
__global__ __launch_bounds__(256, 2) void k_ih(
    const float* __restrict__ x, const unsigned short* __restrict__ w3,
    const float* __restrict__ bif, const float* __restrict__ bhf,
    const float* __restrict__ bib, const float* __restrict__ bhb,
    float* __restrict__ pre) {
  __shared__ float xs[128 * 36];
  __shared__ float bsum[224];
  int tid = threadIdx.x;
  int wv = tid >> 6, l = tid & 63;
  long row0 = (long)blockIdx.x * 128;
  for (int u = tid; u < 224; u += 256) {
    float bv = 0.f;
    if (u < 100) bv = bif[u] + bhf[u];
    else if (u < 200) bv = bib[u - 100] + bhb[u - 100];
    bsum[u] = bv;
  }
  int lr = l & 15;
  int kq = l >> 4;
  f32x4 acc[2][14];
#pragma unroll
  for (int m = 0; m < 2; m++)
#pragma unroll
    for (int n = 0; n < 14; n++) acc[m][n] = (f32x4){0.f, 0.f, 0.f, 0.f};
  for (int ck = 0; ck < 7; ck++) {
    int k0 = ck * 32;
    __syncthreads();
#pragma unroll
    for (int i = 0; i < 8; i++) {
      int u = tid + i * 256;
      int r = u >> 4, kp = u & 15;
      int gk = k0 + 2 * kp;
      float2 v = make_float2(0.f, 0.f);
      if (gk < IN_) v = *(const float2*)(x + (row0 + r) * IN_ + gk);
      *(float2*)(&xs[r * 36 + 2 * kp]) = v;
    }
    __syncthreads();
    short8v A0[2], A1[2], A2[2];
#pragma unroll
    for (int m = 0; m < 2; m++) {
      const float* ap = &xs[(wv * 32 + m * 16 + lr) * 36 + kq * 8];
      float4 fa = *(const float4*)(ap);
      float4 fb = *(const float4*)(ap + 4);
      float f[8] = {fa.x, fa.y, fa.z, fa.w, fb.x, fb.y, fb.z, fb.w};
#pragma unroll
      for (int j = 0; j < 8; j++) {
        unsigned u0 = __float_as_uint(f[j]) & 0xffff0000u;
        float r1 = f[j] - __uint_as_float(u0);
        unsigned u1 = __float_as_uint(r1) & 0xffff0000u;
        float r2 = r1 - __uint_as_float(u1);
        A0[m][j] = (short)(u0 >> 16);
        A1[m][j] = (short)(u1 >> 16);
        A2[m][j] = (short)(__float_as_uint(r2) >> 16);
      }
    }
#pragma unroll
    for (int n = 0; n < 14; n++) {
      int col = n * 16 + lr;
      const unsigned short* bp = w3 + (long)col * 224 + k0 + kq * 8;
      short8v B0 = *(const short8v*)(bp);
      short8v B1 = *(const short8v*)(bp + 50176);
      short8v B2 = *(const short8v*)(bp + 100352);
#pragma unroll
      for (int m = 0; m < 2; m++) {
        f32x4 c = acc[m][n];
        c = __builtin_amdgcn_mfma_f32_16x16x32_bf16(A0[m], B0, c, 0, 0, 0);
        c = __builtin_amdgcn_mfma_f32_16x16x32_bf16(A0[m], B1, c, 0, 0, 0);
        c = __builtin_amdgcn_mfma_f32_16x16x32_bf16(A1[m], B0, c, 0, 0, 0);
        c = __builtin_amdgcn_mfma_f32_16x16x32_bf16(A0[m], B2, c, 0, 0, 0);
        c = __builtin_amdgcn_mfma_f32_16x16x32_bf16(A2[m], B0, c, 0, 0, 0);
        c = __builtin_amdgcn_mfma_f32_16x16x32_bf16(A1[m], B1, c, 0, 0, 0);
        c = __builtin_amdgcn_mfma_f32_16x16x32_bf16(A1[m], B2, c, 0, 0, 0);
        c = __builtin_amdgcn_mfma_f32_16x16x32_bf16(A2[m], B1, c, 0, 0, 0);
        acc[m][n] = c;
      }
    }
  }
#pragma unroll
  for (int m = 0; m < 2; m++) {
    long rbase = row0 + wv * 32 + m * 16 + kq * 4;
#pragma unroll
    for (int n = 0; n < 13; n++) {
      int col = n * 16 + lr;
      if (col < 200) {
        float bv = bsum[col];
#pragma unroll
        for (int r = 0; r < 4; r++)
          pre[(rbase + r) * 200 + col] = acc[m][n][r] + bv;
      }
    }
  }
}

// ---------------- K2: recurrence over b; 8 waves/chain, slices {16,28,28,28},
// fast tanh, 2 barriers/step (round-17 proven).
template <int KO, int KN, bool OW>
__device__ __forceinline__ void rnn8(
    float* __restrict__ p, long step, int row, bool owns, int qidx,
    const float* __restrict__ w, float (*hb)[104], float (*ps)[104]) {
  float wr[KN];
#pragma unroll
  for (int i = 0; i < KN / 4; i++) {
    float4 w4 = *(const float4*)(w + row * HID_ + KO + 4 * i);
    wr[4 * i + 0] = w4.x; wr[4 * i + 1] = w4.y;
    wr[4 * i + 2] = w4.z; wr[4 * i + 3] = w4.w;
  }
  float a = 0.f;
  if (OW) a = p[row];
  for (int s = 0; s < B_; s++) {
    int cur = s & 1;
    float a_next = 0.f;
    if (OW && s < B_ - 1) a_next = p[step + row];
    float ac0 = OW ? a : 0.f, ac1 = 0.f, ac2 = 0.f, ac3 = 0.f;
#pragma unroll
    for (int i = 0; i < KN / 4; i++) {
      float4 h4 = *(const float4*)(&hb[cur][KO + 4 * i]);
      ac0 = fmaf(h4.x, wr[4 * i + 0], ac0);
      ac1 = fmaf(h4.y, wr[4 * i + 1], ac1);
      ac2 = fmaf(h4.z, wr[4 * i + 2], ac2);
      ac3 = fmaf(h4.w, wr[4 * i + 3], ac3);
    }
    float partial = (ac0 + ac1) + (ac2 + ac3);
    if (!OW && owns) ps[qidx][row] = partial;
    __syncthreads();
    if (OW) {
      float tot = partial + ps[0][row] + ps[1][row] + ps[2][row];
      float hnew = fast_tanh(tot);
      if (owns) {
        p[row] = hnew;
        hb[cur ^ 1][row] = hnew;
      }
    }
    __syncthreads();
    p += step;
    a = a_next;
  }
}

__global__ __launch_bounds__(512, 8) void k_rnn(
    float* __restrict__ pre,
    const float* __restrict__ whf, const float* __restrict__ whb) {
  __shared__ __align__(16) float hb[2][104];
  __shared__ __align__(16) float ps[3][104];
  int bid = blockIdx.x;
  int dir = bid >> 9;
  int t = bid & 511;
  const float* w = dir ? whb : whf;
  int tid = threadIdx.x;
  int wv = tid >> 6, lane = tid & 63;
  int grp = wv & 1;
  int kq = wv >> 1;
  int row = grp ? (64 + (lane < 36 ? lane : 35)) : lane;
  bool owns = grp ? (lane < 36) : true;
  long step = dir ? -(long)(T_ * 200) : (long)(T_ * 200);
  float* p = pre + ((long)(dir ? (B_ - 1) : 0) * T_ + t) * 200 + dir * 100;
  if (tid < 104) hb[0][tid] = 0.f;
  __syncthreads();
  if (kq == 0)      rnn8<0, 16, true >(p, step, row, owns, 0, w, hb, ps);
  else if (kq == 1) rnn8<16, 28, false>(p, step, row, owns, 0, w, hb, ps);
  else if (kq == 2) rnn8<44, 28, false>(p, step, row, owns, 1, w, hb, ps);
  else              rnn8<72, 28, false>(p, step, row, owns, 2, w, hb, ps);
}

// ---------------- K3: logits = h @ w_lin^T + b_lin ; softmax over 19. 2 rows/thread.
__global__ __launch_bounds__(256, 4) void k_lin(
    const float* __restrict__ h, const float* __restrict__ wlin,
    const float* __restrict__ blin, float* __restrict__ em) {
  int tid = threadIdx.x;
  long r0 = ((long)blockIdx.x * 256 + tid) * 2;
  const float* h0 = h + r0 * 200;
  float acc0[K_], acc1[K_];
#pragma unroll
  for (int c = 0; c < K_; c++) { float bb = blin[c]; acc0[c] = bb; acc1[c] = bb; }
  for (int kk = 0; kk < 50; kk++) {
    float4 a = *(const float4*)(h0 + 4 * kk);
    float4 b = *(const float4*)(h0 + 200 + 4 * kk);
#pragma unroll
    for (int c = 0; c < K_; c++) {
      float4 wv = *(const float4*)(wlin + c * 200 + 4 * kk);
      acc0[c] += a.x * wv.x + a.y * wv.y + a.z * wv.z + a.w * wv.w;
      acc1[c] += b.x * wv.x + b.y * wv.y + b.z * wv.z + b.w * wv.w;
    }
  }
  float mx0 = acc0[0], mx1 = acc1[0];
#pragma unroll
  for (int c = 1; c < K_; c++) { mx0 = fmaxf(mx0, acc0[c]); mx1 = fmaxf(mx1, acc1[c]); }
  float s0 = 0.f, s1 = 0.f;
#pragma unroll
  for (int c = 0; c < K_; c++) {
    acc0[c] = __expf(acc0[c] - mx0); s0 += acc0[c];
    acc1[c] = __expf(acc1[c] - mx1); s1 += acc1[c];
  }
  float i0 = 1.f / s0, i1 = 1.f / s1;
  float* e0 = em + r0 * K_;
#pragma unroll
  for (int c = 0; c < K_; c++) { e0[c] = acc0[c] * i0; e0[K_ + c] = acc1[c] * i1; }
}

// ---------------- K4: TWO sequences per block (b, b+128), chains interleaved in
// each wave so one chain's bpermute latency is hidden under the other's compute.
// wave0: logZ both (scaled-prob, per-step pow2 renorm; Ecol shared).
// wave1: Viterbi both (Tt shared) + backtracks. Dynamic LDS ~96.6 KB.
__global__ __launch_bounds__(128, 1) void k_crf(
    const float* __restrict__ em, const int* __restrict__ y,
    const float* __restrict__ st_g, const float* __restrict__ en_g,
    const float* __restrict__ tr_g,
    float* __restrict__ part, int* __restrict__ cnt,
    float* __restrict__ out) {
  extern __shared__ __align__(16) float S[];
  unsigned char* hl0 = (unsigned char*)S + HL0_B;
  unsigned char* hl1 = (unsigned char*)S + HL1_B;
  int b0 = blockIdx.x, b1 = blockIdx.x + 128;
  int tid = threadIdx.x;
  int wv = tid >> 6, lane = tid & 63;
  const float4* eg0 = (const float4*)(em + (long)b0 * T_ * K_);
  const float4* eg1 = (const float4*)(em + (long)b1 * T_ * K_);
  for (int u = tid; u < T_ * K_ / 4; u += 128) {
    ((float4*)(S + ES0_OFF))[u] = eg0[u];
    ((float4*)(S + ES1_OFF))[u] = eg1[u];
  }
  for (int u = tid; u < K_ * K_; u += 128) S[TRS_OFF + u] = tr_g[u];
  if (tid < K_) { S[STL_OFF + tid] = st_g[tid]; S[ENL_OFF + tid] = en_g[tid]; }
  __syncthreads();
  const float* es0 = S + ES0_OFF;
  const float* es1 = S + ES1_OFF;
  const float* trs = S + TRS_OFF;
  const float* stl = S + STL_OFF;
  const float* enl = S + ENL_OFF;
  const int* yb0 = y + (long)b0 * T_;
  const int* yb1 = y + (long)b1 * T_;
  int l0 = T_, l1 = T_;
  for (int u = lane; u < T_; u += 64) {
    if (yb0[u] == -1 && u < l0) l0 = u;
    if (yb1[u] == -1 && u < l1) l1 = u;
  }
#pragma unroll
  for (int off = 32; off; off >>= 1) {
    int o0 = __shfl_xor(l0, off, 64); l0 = l0 < o0 ? l0 : o0;
    int o1 = __shfl_xor(l1, off, 64); l1 = l1 < o1 ? l1 : o1;
  }
  int len0 = l0, len1 = l1;             // >= 1, wave-uniform
  int lenM = len0 > len1 ? len0 : len1;
  int jj = lane < K_ ? lane : K_ - 1;
  bool act = lane < K_;

  if (wv == 0) {
    // ---- gold scores (parallel gathers)
    float g0 = 0.f, g1 = 0.f;
    for (int t = 1 + lane; t < len0; t += 64)
      g0 += trs[yb0[t - 1] * K_ + yb0[t]] + es0[t * K_ + yb0[t]];
    for (int t = 1 + lane; t < len1; t += 64)
      g1 += trs[yb1[t - 1] * K_ + yb1[t]] + es1[t * K_ + yb1[t]];
#pragma unroll
    for (int off = 32; off; off >>= 1) {
      g0 += __shfl_xor(g0, off, 64);
      g1 += __shfl_xor(g1, off, 64);
    }
    float num0 = stl[yb0[0]] + es0[yb0[0]] + g0 + enl[yb0[len0 - 1]];
    float num1 = stl[yb1[0]] + es1[yb1[0]] + g1 + enl[yb1[len1 - 1]];
    // ---- dual serial logZ (Ecol shared)
    float Ecol[K_];
#pragma unroll
    for (int i = 0; i < K_; i++) Ecol[i] = __expf(trs[i * K_ + jj]);
    float P0 = __expf(stl[jj] + es0[jj]);
    float P1 = __expf(stl[jj] + es1[jj]);
    int kc0 = 0, kc1 = 0;
    float ee0 = __expf(es0[K_ + jj]);
    float ee1 = __expf(es1[K_ + jj]);
    for (int t = 1; t < lenM; t++) {
      bool q0 = t < len0, q1 = t < len1;
      float pr0[K_], pr1[K_];
      if (q0) {
#pragma unroll
        for (int i = 0; i < K_; i++) pr0[i] = bcast_f(P0, i);
      }
      if (q1) {
#pragma unroll
        for (int i = 0; i < K_; i++) pr1[i] = bcast_f(P1, i);
      }
      int tn = (t + 1 < T_) ? t + 1 : T_ - 1;
      if (q0) {
        float e_next = es0[tn * K_ + jj];
        unsigned pb = __float_as_uint(pr0[0]);
        int ex = (int)((pb >> 23) & 0xff);
        float scale = __uint_as_float((unsigned)(254 - ex) << 23);
        kc0 += ex - 127;
        float a0 = 0.f, a1 = 0.f, a2 = 0.f, a3 = 0.f;
#pragma unroll
        for (int i = 0; i < K_; i++) {
          if ((i & 3) == 0)      a0 = fmaf(pr0[i], Ecol[i], a0);
          else if ((i & 3) == 1) a1 = fmaf(pr0[i], Ecol[i], a1);
          else if ((i & 3) == 2) a2 = fmaf(pr0[i], Ecol[i], a2);
          else                   a3 = fmaf(pr0[i], Ecol[i], a3);
        }
        P0 = ((((a0 + a1) + (a2 + a3)) * ee0)) * scale;
        ee0 = __expf(e_next);
      }
      if (q1) {
        float e_next = es1[tn * K_ + jj];
        unsigned pb = __float_as_uint(pr1[0]);
        int ex = (int)((pb >> 23) & 0xff);
        float scale = __uint_as_float((unsigned)(254 - ex) << 23);
        kc1 += ex - 127;
        float a0 = 0.f, a1 = 0.f, a2 = 0.f, a3 = 0.f;
#pragma unroll
        for (int i = 0; i < K_; i++) {
          if ((i & 3) == 0)      a0 = fmaf(pr1[i], Ecol[i], a0);
          else if ((i & 3) == 1) a1 = fmaf(pr1[i], Ecol[i], a1);
          else if ((i & 3) == 2) a2 = fmaf(pr1[i], Ecol[i], a2);
          else                   a3 = fmaf(pr1[i], Ecol[i], a3);
        }
        P1 = ((((a0 + a1) + (a2 + a3)) * ee1)) * scale;
        ee1 = __expf(e_next);
      }
    }
    // ---- finalize both logZ
    {
      float pr0[K_], pr1[K_];
#pragma unroll
      for (int i = 0; i < K_; i++) pr0[i] = bcast_f(P0, i);
#pragma unroll
      for (int i = 0; i < K_; i++) pr1[i] = bcast_f(P1, i);
      float s0 = 0.f, s1 = 0.f;
#pragma unroll
      for (int i = 0; i < K_; i++) {
        float ene = __expf(enl[i]);
        s0 += pr0[i] * ene;
        s1 += pr1[i] * ene;
      }
      if (lane == 0) {
        part[b0] = __logf(s0) + (float)kc0 * 0.6931471805599453f - num0;
        part[b1] = __logf(s1) + (float)kc1 * 0.6931471805599453f - num1;
      }
    }
    int old = -1;
    if (lane == 0) { __threadfence(); old = atomicAdd(cnt, 1); }
    old = __shfl(old, 0, 64);
    if (old == 127) {   // last of 128 blocks: deterministic fixed-order sum
      __threadfence();
      float s = 0.f;
      for (int u = lane; u < B_; u += 64) s += part[u];
#pragma unroll
      for (int off = 32; off; off >>= 1) s += __shfl_xor(s, off, 64);
      if (lane == 0) out[0] = s;
    }
  } else {
    // ---- dual Viterbi (Tt shared)
    float Tt[K_];
#pragma unroll
    for (int i = 0; i < K_; i++) Tt[i] = trs[i * K_ + jj];
    float V0 = stl[jj] + es0[jj];
    float V1 = stl[jj] + es1[jj];
    float e0c = es0[K_ + jj];
    float e1c = es1[K_ + jj];
    for (int t = 1; t < lenM; t++) {
      bool q0 = t < len0, q1 = t < len1;
      float vr0[K_], vr1[K_];
      if (q0) {
#pragma unroll
        for (int i = 0; i < K_; i++) vr0[i] = bcast_f(V0, i);
      }
      if (q1) {
#pragma unroll
        for (int i = 0; i < K_; i++) vr1[i] = bcast_f(V1, i);
      }
      int tn = (t + 1 < T_) ? t + 1 : T_ - 1;
      if (q0) {
        float e_next = es0[tn * K_ + jj];
        float c0 = -1e30f, c1 = -1e30f, c2 = -1e30f, c3 = -1e30f;
        int a0 = 0, a1 = 5, a2 = 10, a3 = 15;
#pragma unroll
        for (int i = 0; i < 5; i++)  { float c = vr0[i] + Tt[i]; if (c > c0) { c0 = c; a0 = i; } }
#pragma unroll
        for (int i = 5; i < 10; i++) { float c = vr0[i] + Tt[i]; if (c > c1) { c1 = c; a1 = i; } }
#pragma unroll
        for (int i = 10; i < 15; i++){ float c = vr0[i] + Tt[i]; if (c > c2) { c2 = c; a2 = i; } }
#pragma unroll
        for (int i = 15; i < 19; i++){ float c = vr0[i] + Tt[i]; if (c > c3) { c3 = c; a3 = i; } }
        if (c1 > c0) { c0 = c1; a0 = a1; }
        if (c2 > c0) { c0 = c2; a0 = a2; }
        if (c3 > c0) { c0 = c3; a0 = a3; }
        if (act) hl0[(t - 1) * K_ + lane] = (unsigned char)a0;
        V0 = c0 + e0c;
        e0c = e_next;
      }
      if (q1) {
        float e_next = es1[tn * K_ + jj];
        float c0 = -1e30f, c1 = -1e30f, c2 = -1e30f, c3 = -1e30f;
        int a0 = 0, a1 = 5, a2 = 10, a3 = 15;
#pragma unroll
        for (int i = 0; i < 5; i++)  { float c = vr1[i] + Tt[i]; if (c > c0) { c0 = c; a0 = i; } }
#pragma unroll
        for (int i = 5; i < 10; i++) { float c = vr1[i] + Tt[i]; if (c > c1) { c1 = c; a1 = i; } }
#pragma unroll
        for (int i = 10; i < 15; i++){ float c = vr1[i] + Tt[i]; if (c > c2) { c2 = c; a2 = i; } }
#pragma unroll
        for (int i = 15; i < 19; i++){ float c = vr1[i] + Tt[i]; if (c > c3) { c3 = c; a3 = i; } }
        if (c1 > c0) { c0 = c1; a0 = a1; }
        if (c2 > c0) { c0 = c2; a0 = a2; }
        if (c3 > c0) { c0 = c3; a0 = a3; }
        if (act) hl1[(t - 1) * K_ + lane] = (unsigned char)a0;
        V1 = c0 + e1c;
        e1c = e_next;
      }
    }
    // ---- final argmax + backtrack, sequence 0 then 1
    {
      float vr[K_];
#pragma unroll
      for (int i = 0; i < K_; i++) vr[i] = bcast_f(V0, i);
      float bb = vr[0] + enl[0]; int aa = 0;
#pragma unroll
      for (int i = 1; i < K_; i++) {
        float c = vr[i] + enl[i];
        if (c > bb) { bb = c; aa = i; }
      }
      float* ob = out + 1 + (long)b0 * T_;
      for (int u = lane; u < T_; u += 64)
        if (u >= len0) ob[u] = -1.f;
      int tag = aa;
      if (lane == 0) ob[len0 - 1] = (float)tag;
      int vc = (act && len0 >= 2) ? (int)hl0[(len0 - 2) * K_ + lane] : 0;
      for (int ti = len0 - 2; ti >= 0; ti--) {
        int vn = 0;
        if (ti > 0 && act) vn = (int)hl0[(ti - 1) * K_ + lane];
        int ts = __builtin_amdgcn_readfirstlane(tag);
        tag = __builtin_amdgcn_readlane(vc, ts);
        if (lane == 0) ob[ti] = (float)tag;
        vc = vn;
      }
    }
    {
      float vr[K_];
#pragma unroll
      for (int i = 0; i < K_; i++) vr[i] = bcast_f(V1, i);
      float bb = vr[0] + enl[0]; int aa = 0;
#pragma unroll
      for (int i = 1; i < K_; i++) {
        float c = vr[i] + enl[i];
        if (c > bb) { bb = c; aa = i; }
      }
      float* ob = out + 1 + (long)b1 * T_;
      for (int u = lane; u < T_; u += 64)
        if (u >= len1) ob[u] = -1.f;
      int tag = aa;
      if (lane == 0) ob[len1 - 1] = (float)tag;
      int vc = (act && len1 >= 2) ? (int)hl1[(len1 - 2) * K_ + lane] : 0;
      for (int ti = len1 - 2; ti >= 0; ti--) {
        int vn = 0;
        if (ti > 0 && act) vn = (int)hl1[(ti - 1) * K_ + lane];
        int ts = __builtin_amdgcn_readfirstlane(tag);
        tag = __builtin_amdgcn_readlane(vc, ts);
        if (lane == 0) ob[ti] = (float)tag;
        vc = vn;
      }
    }
  }
}

extern "C" void kernel_launch(void* const* d_in, const int* in_sizes, int n_in,
                              void* d_out, int out_size, void* d_ws, size_t ws_size,
                              hipStream_t stream) {
  const float* x      = (const float*)d_in[0];
  const int*   y      = (const int*)d_in[1];
  const float* w_ih_f = (const float*)d_in[2];
  const float* w_hh_f = (const float*)d_in[3];
  const float* b_ih_f = (const float*)d_in[4];
  const float* b_hh_f = (const float*)d_in[5];
  const float* w_ih_b = (const float*)d_in[6];
  const float* w_hh_b = (const float*)d_in[7];
  const float* b_ih_b = (const float*)d_in[8];
  const float* b_hh_b = (const float*)d_in[9];
  const float* w_lin  = (const float*)d_in[10];
  const float* b_lin  = (const float*)d_in[11];
  const float* st     = (const float*)d_in[12];
  const float* en     = (const float*)d_in[13];
  const float* trans  = (const float*)d_in[14];

  char* ws = (char*)d_ws;
  const size_t PRE_OFF  = 0;                          // 131072*200*4 = 104857600
  const size_t EM_OFF   = 104857600;                  // 131072*19*4  = 9961472
  const size_t PART_OFF = EM_OFF + 9961472;           // 1024
  const size_t CNT_OFF  = PART_OFF + 1024;            // 4
  float* PRE  = (float*)(ws + PRE_OFF);
  float* EM   = (float*)(ws + EM_OFF);
  float* PART = (float*)(ws + PART_OFF);
  int*   CNT  = (int*)(ws + CNT_OFF);
  unsigned short* W3 = (unsigned short*)(ws + EM_OFF);  // consumed before k_lin writes EM
  float* out  = (float*)d_out;

  hipFuncSetAttribute((const void*)k_crf,
                      hipFuncAttributeMaxDynamicSharedMemorySize, CRF2_LDS_B);
  hipMemsetAsync((void*)CNT, 0, sizeof(int), stream);
  k_wprep<<<196, 256, 0, stream>>>(w_ih_f, w_ih_b, W3);
  k_ih<<<1024, 256, 0, stream>>>(x, W3, b_ih_f, b_hh_f, b_ih_b, b_hh_b, PRE);
  k_rnn<<<1024, 512, 0, stream>>>(PRE, w_hh_f, w_hh_b);
  k_lin<<<256, 256, 0, stream>>>(PRE, w_lin, b_lin, EM);
  k_crf<<<128, 128, CRF2_LDS_B, stream>>>(EM, y, st, en, trans, PART, CNT, out);
}

// Round 25
// 580.048 us; speedup vs baseline: 1.3548x; 1.3548x over previous
//
#include <hip/hip_runtime.h>
#include <hip/hip_bf16.h>

#define B_ 256
#define T_ 512
#define IN_ 202
#define HID_ 100
#define K_ 19

typedef __attribute__((ext_vector_type(8))) short short8v;
typedef __attribute__((ext_vector_type(4))) float f32x4;

__device__ __forceinline__ float rl_f(float v, int l) {
  return __int_as_float(__builtin_amdgcn_readlane(__float_as_int(v), l));
}
// register->register broadcast of lane l via LDS crossbar (no storage, no SGPR hazard)
__device__ __forceinline__ float bcast_f(float v, int l) {
  return __int_as_float(__builtin_amdgcn_ds_bpermute(l * 4, __float_as_int(v)));
}
// tanh(x) = 1 - 2/(exp(2x)+1): 5 instrs vs ~25 for libm; exact saturation at +-1.
__device__ __forceinline__ float fast_tanh(float x) {
  float t = __expf(2.f * x);
  float r = __builtin_amdgcn_rcpf(t + 1.f);
  return fmaf(-2.f, r, 1.f);
}

// ---------------- K0: split [wf;wb] (200x202) into 3 exact bf16 planes, padded to 224x224.
__global__ __launch_bounds__(256, 1) void k_wprep(
    const float* __restrict__ wf, const float* __restrict__ wb,
    unsigned short* __restrict__ w3) {
  int idx = blockIdx.x * 256 + threadIdx.x;
  if (idx >= 224 * 224) return;
  int c = idx / 224, k = idx - (idx / 224) * 224;
  float v = 0.f;
  if (k < IN_) {
    if (c < 100) v = wf[c * IN_ + k];
    else if (c < 200) v = wb[(c - 100) * IN_ + k];
  }
  unsigned u0 = __float_as_uint(v) & 0xffff0000u;
  float r1 = v - __uint_as_float(u0);
  unsigned u1 = __float_as_uint(r1) & 0xffff0000u;
  float r2 = r1 - __uint_as_float(u1);
  w3[idx] = (unsigned short)(u0 >> 16);
  w3[50176 + idx] = (unsigned short)(u1 >> 16);
  w3[100352 + idx] = (unsigned short)(__float_as_uint(r2) >> 16);
}

// ---------------- K1: pre = x . [wf;wb]^T + bias via bf16-split MFMA.
// SINGLE PASS over x: 1024 blocks x 128 rows; wave owns 32 rows (2 m-tiles)
// x ALL 14 n-tiles. acc[2][14] = 112 VGPR. x staged once per K-chunk.
__global__ __launch_bounds__(256, 2) void k_ih(
    const float* __restrict__ x, const unsigned short* __restrict__ w3,
    const float* __restrict__ bif, const float* __restrict__ bhf,
    const float* __restrict__ bib, const float* __restrict__ bhb,
    float* __restrict__ pre) {
  __shared__ float xs[128 * 36];
  __shared__ float bsum[224];
  int tid = threadIdx.x;
  int wv = tid >> 6, l = tid & 63;
  long row0 = (long)blockIdx.x * 128;
  for (int u = tid; u < 224; u += 256) {
    float bv = 0.f;
    if (u < 100) bv = bif[u] + bhf[u];
    else if (u < 200) bv = bib[u - 100] + bhb[u - 100];
    bsum[u] = bv;
  }
  int lr = l & 15;
  int kq = l >> 4;
  f32x4 acc[2][14];
#pragma unroll
  for (int m = 0; m < 2; m++)
#pragma unroll
    for (int n = 0; n < 14; n++) acc[m][n] = (f32x4){0.f, 0.f, 0.f, 0.f};
  for (int ck = 0; ck < 7; ck++) {
    int k0 = ck * 32;
    __syncthreads();
#pragma unroll
    for (int i = 0; i < 8; i++) {
      int u = tid + i * 256;
      int r = u >> 4, kp = u & 15;
      int gk = k0 + 2 * kp;
      float2 v = make_float2(0.f, 0.f);
      if (gk < IN_) v = *(const float2*)(x + (row0 + r) * IN_ + gk);
      *(float2*)(&xs[r * 36 + 2 * kp]) = v;
    }
    __syncthreads();
    // A fragments (2 m-tiles), exact 3-way bf16 split in-register
    short8v A0[2], A1[2], A2[2];
#pragma unroll
    for (int m = 0; m < 2; m++) {
      const float* ap = &xs[(wv * 32 + m * 16 + lr) * 36 + kq * 8];
      float4 fa = *(const float4*)(ap);
      float4 fb = *(const float4*)(ap + 4);
      float f[8] = {fa.x, fa.y, fa.z, fa.w, fb.x, fb.y, fb.z, fb.w};
#pragma unroll
      for (int j = 0; j < 8; j++) {
        unsigned u0 = __float_as_uint(f[j]) & 0xffff0000u;
        float r1 = f[j] - __uint_as_float(u0);
        unsigned u1 = __float_as_uint(r1) & 0xffff0000u;
        float r2 = r1 - __uint_as_float(u1);
        A0[m][j] = (short)(u0 >> 16);
        A1[m][j] = (short)(u1 >> 16);
        A2[m][j] = (short)(__float_as_uint(r2) >> 16);
      }
    }
#pragma unroll
    for (int n = 0; n < 14; n++) {
      int col = n * 16 + lr;
      const unsigned short* bp = w3 + (long)col * 224 + k0 + kq * 8;
      short8v B0 = *(const short8v*)(bp);
      short8v B1 = *(const short8v*)(bp + 50176);
      short8v B2 = *(const short8v*)(bp + 100352);
#pragma unroll
      for (int m = 0; m < 2; m++) {
        f32x4 c = acc[m][n];
        c = __builtin_amdgcn_mfma_f32_16x16x32_bf16(A0[m], B0, c, 0, 0, 0);
        c = __builtin_amdgcn_mfma_f32_16x16x32_bf16(A0[m], B1, c, 0, 0, 0);
        c = __builtin_amdgcn_mfma_f32_16x16x32_bf16(A1[m], B0, c, 0, 0, 0);
        c = __builtin_amdgcn_mfma_f32_16x16x32_bf16(A0[m], B2, c, 0, 0, 0);
        c = __builtin_amdgcn_mfma_f32_16x16x32_bf16(A2[m], B0, c, 0, 0, 0);
        c = __builtin_amdgcn_mfma_f32_16x16x32_bf16(A1[m], B1, c, 0, 0, 0);
        c = __builtin_amdgcn_mfma_f32_16x16x32_bf16(A1[m], B2, c, 0, 0, 0);
        c = __builtin_amdgcn_mfma_f32_16x16x32_bf16(A2[m], B1, c, 0, 0, 0);
        acc[m][n] = c;
      }
    }
  }
#pragma unroll
  for (int m = 0; m < 2; m++) {
    long rbase = row0 + wv * 32 + m * 16 + kq * 4;
#pragma unroll
    for (int n = 0; n < 13; n++) {  // n=13 -> cols 208..223 all padding
      int col = n * 16 + lr;
      if (col < 200) {
        float bv = bsum[col];
#pragma unroll
        for (int r = 0; r < 4; r++)
          pre[(rbase + r) * 200 + col] = acc[m][n][r] + bv;
      }
    }
  }
}

// ---------------- K2: recurrence over b (256 steps); 8 waves per (t,dir) chain.
// K-slices BALANCED {16,28,28,28}; fast tanh; 2 barriers/step.
template <int KO, int KN, bool OW>
__device__ __forceinline__ void rnn8(
    float* __restrict__ p, long step, int row, bool owns, int qidx,
    const float* __restrict__ w, float (*hb)[104], float (*ps)[104]) {
  float wr[KN];
#pragma unroll
  for (int i = 0; i < KN / 4; i++) {
    float4 w4 = *(const float4*)(w + row * HID_ + KO + 4 * i);
    wr[4 * i + 0] = w4.x; wr[4 * i + 1] = w4.y;
    wr[4 * i + 2] = w4.z; wr[4 * i + 3] = w4.w;
  }
  float a = 0.f;
  if (OW) a = p[row];
  for (int s = 0; s < B_; s++) {
    int cur = s & 1;
    float a_next = 0.f;
    if (OW && s < B_ - 1) a_next = p[step + row];
    float ac0 = OW ? a : 0.f, ac1 = 0.f, ac2 = 0.f, ac3 = 0.f;
#pragma unroll
    for (int i = 0; i < KN / 4; i++) {
      float4 h4 = *(const float4*)(&hb[cur][KO + 4 * i]);  // uniform -> broadcast
      ac0 = fmaf(h4.x, wr[4 * i + 0], ac0);
      ac1 = fmaf(h4.y, wr[4 * i + 1], ac1);
      ac2 = fmaf(h4.z, wr[4 * i + 2], ac2);
      ac3 = fmaf(h4.w, wr[4 * i + 3], ac3);
    }
    float partial = (ac0 + ac1) + (ac2 + ac3);
    if (!OW && owns) ps[qidx][row] = partial;
    __syncthreads();
    if (OW) {
      float tot = partial + ps[0][row] + ps[1][row] + ps[2][row];
      float hnew = fast_tanh(tot);
      if (owns) {
        p[row] = hnew;
        hb[cur ^ 1][row] = hnew;
      }
    }
    __syncthreads();
    p += step;
    a = a_next;
  }
}

__global__ __launch_bounds__(512, 8) void k_rnn(
    float* __restrict__ pre,
    const float* __restrict__ whf, const float* __restrict__ whb) {
  __shared__ __align__(16) float hb[2][104];
  __shared__ __align__(16) float ps[3][104];
  int bid = blockIdx.x;
  int dir = bid >> 9;
  int t = bid & 511;
  const float* w = dir ? whb : whf;
  int tid = threadIdx.x;
  int wv = tid >> 6, lane = tid & 63;
  int grp = wv & 1;     // 0: rows 0..63, 1: rows 64..99
  int kq = wv >> 1;     // K slice 0..3 (0 = owner)
  int row = grp ? (64 + (lane < 36 ? lane : 35)) : lane;
  bool owns = grp ? (lane < 36) : true;
  long step = dir ? -(long)(T_ * 200) : (long)(T_ * 200);
  float* p = pre + ((long)(dir ? (B_ - 1) : 0) * T_ + t) * 200 + dir * 100;
  if (tid < 104) hb[0][tid] = 0.f;
  __syncthreads();
  if (kq == 0)      rnn8<0, 16, true >(p, step, row, owns, 0, w, hb, ps);
  else if (kq == 1) rnn8<16, 28, false>(p, step, row, owns, 0, w, hb, ps);
  else if (kq == 2) rnn8<44, 28, false>(p, step, row, owns, 1, w, hb, ps);
  else              rnn8<72, 28, false>(p, step, row, owns, 2, w, hb, ps);
}

// ---------------- K3: logits = h @ w_lin^T + b_lin ; softmax over 19. 2 rows/thread.
__global__ __launch_bounds__(256, 4) void k_lin(
    const float* __restrict__ h, const float* __restrict__ wlin,
    const float* __restrict__ blin, float* __restrict__ em) {
  int tid = threadIdx.x;
  long r0 = ((long)blockIdx.x * 256 + tid) * 2;
  const float* h0 = h + r0 * 200;
  float acc0[K_], acc1[K_];
#pragma unroll
  for (int c = 0; c < K_; c++) { float bb = blin[c]; acc0[c] = bb; acc1[c] = bb; }
  for (int kk = 0; kk < 50; kk++) {
    float4 a = *(const float4*)(h0 + 4 * kk);
    float4 b = *(const float4*)(h0 + 200 + 4 * kk);
#pragma unroll
    for (int c = 0; c < K_; c++) {
      float4 wv = *(const float4*)(wlin + c * 200 + 4 * kk);  // uniform -> s_load
      acc0[c] += a.x * wv.x + a.y * wv.y + a.z * wv.z + a.w * wv.w;
      acc1[c] += b.x * wv.x + b.y * wv.y + b.z * wv.z + b.w * wv.w;
    }
  }
  float mx0 = acc0[0], mx1 = acc1[0];
#pragma unroll
  for (int c = 1; c < K_; c++) { mx0 = fmaxf(mx0, acc0[c]); mx1 = fmaxf(mx1, acc1[c]); }
  float s0 = 0.f, s1 = 0.f;
#pragma unroll
  for (int c = 0; c < K_; c++) {
    acc0[c] = __expf(acc0[c] - mx0); s0 += acc0[c];
    acc1[c] = __expf(acc1[c] - mx1); s1 += acc1[c];
  }
  float i0 = 1.f / s0, i1 = 1.f / s1;
  float* e0 = em + r0 * K_;
#pragma unroll
  for (int c = 0; c < K_; c++) { e0[c] = acc0[c] * i0; e0[K_ + c] = acc1[c] * i1; }
}

// ---------------- K4: 2 waves per b; bpermute state broadcast. wave0: logZ in
// scaled probability space (exact power-of-2 renorm per step) + parallel gold
// gather. wave1: Viterbi forward + backtrack. (Best measured: ~199 us.)
__global__ __launch_bounds__(128, 1) void k_crf(
    const float* __restrict__ em, const int* __restrict__ y,
    const float* __restrict__ st_g, const float* __restrict__ en_g,
    const float* __restrict__ tr_g,
    float* __restrict__ part, int* __restrict__ cnt,
    float* __restrict__ out) {
  __shared__ __align__(16) float es[T_ * K_];
  __shared__ int ys[T_];
  __shared__ float trs[K_ * K_];
  __shared__ float st[K_], en[K_];
  __shared__ unsigned char hl[511 * K_ + 13];
  int b = blockIdx.x;
  int tid = threadIdx.x;
  int wv = tid >> 6, lane = tid & 63;
  const float4* eb4 = (const float4*)(em + (long)b * T_ * K_);
  for (int u = tid; u < T_ * K_ / 4; u += 128) ((float4*)es)[u] = eb4[u];
  for (int u = tid; u < T_; u += 128) ys[u] = y[b * T_ + u];
  for (int u = tid; u < K_ * K_; u += 128) trs[u] = tr_g[u];
  if (tid < K_) { st[tid] = st_g[tid]; en[tid] = en_g[tid]; }
  __syncthreads();
  int lmin = T_;
  for (int u = lane; u < T_; u += 64)
    if (ys[u] == -1 && u < lmin) lmin = u;
#pragma unroll
  for (int off = 32; off; off >>= 1) {
    int o = __shfl_xor(lmin, off, 64);
    lmin = lmin < o ? lmin : o;
  }
  int len = lmin;  // >= 1

  int jj = lane < K_ ? lane : K_ - 1;
  bool act = lane < K_;
  float enr[20];
#pragma unroll
  for (int q = 0; q < 5; q++) {
    float4 e4 = (q < 4) ? *(const float4*)(&en[4 * q])
                        : make_float4(en[16], en[17], en[18], -1e30f);
    enr[4 * q] = e4.x; enr[4 * q + 1] = e4.y; enr[4 * q + 2] = e4.z; enr[4 * q + 3] = e4.w;
  }

  if (wv == 0) {
    float gacc = 0.f;
    for (int t = 1 + lane; t < len; t += 64)
      gacc += trs[ys[t - 1] * K_ + ys[t]] + es[t * K_ + ys[t]];
#pragma unroll
    for (int off = 32; off; off >>= 1) gacc += __shfl_xor(gacc, off, 64);
    int y0 = ys[0], ylast = ys[len - 1];
    float num = st[y0] + es[y0] + gacc + en[ylast];
    float Ecol[K_];
#pragma unroll
    for (int i = 0; i < K_; i++) Ecol[i] = __expf(trs[i * K_ + jj]);
    float P = __expf(st[jj] + es[jj]);
    int kacc = 0;
    float ee = __expf(es[K_ + jj]);
    for (int t = 1; t < len; t++) {
      float pr[K_];
#pragma unroll
      for (int i = 0; i < K_; i++) pr[i] = bcast_f(P, i);
      int tn = (t + 1 < T_) ? t + 1 : T_ - 1;
      float e_next = es[tn * K_ + jj];
      unsigned pb = __float_as_uint(pr[0]);
      int ex = (int)((pb >> 23) & 0xff);
      float scale = __uint_as_float((unsigned)(254 - ex) << 23);
      kacc += ex - 127;
      float a0 = 0.f, a1 = 0.f, a2 = 0.f, a3 = 0.f;
#pragma unroll
      for (int i = 0; i < K_; i++) {
        if ((i & 3) == 0)      a0 = fmaf(pr[i], Ecol[i], a0);
        else if ((i & 3) == 1) a1 = fmaf(pr[i], Ecol[i], a1);
        else if ((i & 3) == 2) a2 = fmaf(pr[i], Ecol[i], a2);
        else                   a3 = fmaf(pr[i], Ecol[i], a3);
      }
      P = ((((a0 + a1) + (a2 + a3)) * ee)) * scale;
      ee = __expf(e_next);
    }
    {
      float pr[K_];
#pragma unroll
      for (int i = 0; i < K_; i++) pr[i] = bcast_f(P, i);
      float sm = 0.f;
#pragma unroll
      for (int i = 0; i < K_; i++) sm += pr[i] * __expf(enr[i]);
      if (lane == 0) part[b] = __logf(sm) + (float)kacc * 0.6931471805599453f - num;
    }
    int old = -1;
    if (lane == 0) { __threadfence(); old = atomicAdd(cnt, 1); }
    old = __shfl(old, 0, 64);
    if (old == B_ - 1) {
      __threadfence();
      float s = 0.f;
      for (int u = lane; u < B_; u += 64) s += part[u];
#pragma unroll
      for (int off = 32; off; off >>= 1) s += __shfl_xor(s, off, 64);
      if (lane == 0) out[0] = s;
    }
  } else {
    float Tt[K_];
#pragma unroll
    for (int i = 0; i < K_; i++) Tt[i] = trs[i * K_ + jj];
    float V = st[jj] + es[jj];
    float e = es[K_ + jj];
    for (int t = 1; t < len; t++) {
      float vr[K_];
#pragma unroll
      for (int i = 0; i < K_; i++) vr[i] = bcast_f(V, i);
      int tn = (t + 1 < T_) ? t + 1 : T_ - 1;
      float e_next = es[tn * K_ + jj];
      float b0 = -1e30f, b1 = -1e30f, b2 = -1e30f, b3 = -1e30f;
      int a0 = 0, a1 = 5, a2 = 10, a3 = 15;
#pragma unroll
      for (int i = 0; i < 5; i++)  { float c = vr[i] + Tt[i]; if (c > b0) { b0 = c; a0 = i; } }
#pragma unroll
      for (int i = 5; i < 10; i++) { float c = vr[i] + Tt[i]; if (c > b1) { b1 = c; a1 = i; } }
#pragma unroll
      for (int i = 10; i < 15; i++){ float c = vr[i] + Tt[i]; if (c > b2) { b2 = c; a2 = i; } }
#pragma unroll
      for (int i = 15; i < 19; i++){ float c = vr[i] + Tt[i]; if (c > b3) { b3 = c; a3 = i; } }
      if (b1 > b0) { b0 = b1; a0 = a1; }
      if (b2 > b0) { b0 = b2; a0 = a2; }
      if (b3 > b0) { b0 = b3; a0 = a3; }
      if (act) hl[(t - 1) * K_ + lane] = (unsigned char)a0;
      V = b0 + e;
      e = e_next;
    }
    int aa;
    {
      float vr[K_];
#pragma unroll
      for (int i = 0; i < K_; i++) vr[i] = bcast_f(V, i);
      float bb = vr[0] + enr[0]; aa = 0;
#pragma unroll
      for (int i = 1; i < K_; i++) {
        float c = vr[i] + enr[i];
        if (c > bb) { bb = c; aa = i; }
      }
    }
    float* ob = out + 1 + (long)b * T_;
    for (int u = lane; u < T_; u += 64)
      if (u >= len) ob[u] = -1.f;
    int tag = aa;
    if (lane == 0) ob[len - 1] = (float)tag;
    int vc = (act && len >= 2) ? (int)hl[(len - 2) * K_ + lane] : 0;
    for (int ti = len - 2; ti >= 0; ti--) {
      int vn = 0;
      if (ti > 0 && act) vn = (int)hl[(ti - 1) * K_ + lane];
      int ts = __builtin_amdgcn_readfirstlane(tag);
      tag = __builtin_amdgcn_readlane(vc, ts);
      if (lane == 0) ob[ti] = (float)tag;
      vc = vn;
    }
  }
}

extern "C" void kernel_launch(void* const* d_in, const int* in_sizes, int n_in,
                              void* d_out, int out_size, void* d_ws, size_t ws_size,
                              hipStream_t stream) {
  const float* x      = (const float*)d_in[0];
  const int*   y      = (const int*)d_in[1];
  const float* w_ih_f = (const float*)d_in[2];
  const float* w_hh_f = (const float*)d_in[3];
  const float* b_ih_f = (const float*)d_in[4];
  const float* b_hh_f = (const float*)d_in[5];
  const float* w_ih_b = (const float*)d_in[6];
  const float* w_hh_b = (const float*)d_in[7];
  const float* b_ih_b = (const float*)d_in[8];
  const float* b_hh_b = (const float*)d_in[9];
  const float* w_lin  = (const float*)d_in[10];
  const float* b_lin  = (const float*)d_in[11];
  const float* st     = (const float*)d_in[12];
  const float* en     = (const float*)d_in[13];
  const float* trans  = (const float*)d_in[14];

  char* ws = (char*)d_ws;
  const size_t PRE_OFF  = 0;                          // 131072*200*4 = 104857600
  const size_t EM_OFF   = 104857600;                  // 131072*19*4  = 9961472
  const size_t PART_OFF = EM_OFF + 9961472;           // 1024
  const size_t CNT_OFF  = PART_OFF + 1024;            // 4
  float* PRE  = (float*)(ws + PRE_OFF);
  float* EM   = (float*)(ws + EM_OFF);
  float* PART = (float*)(ws + PART_OFF);
  int*   CNT  = (int*)(ws + CNT_OFF);
  unsigned short* W3 = (unsigned short*)(ws + EM_OFF);  // consumed before k_lin writes EM
  float* out  = (float*)d_out;

  hipMemsetAsync((void*)CNT, 0, sizeof(int), stream);
  k_wprep<<<196, 256, 0, stream>>>(w_ih_f, w_ih_b, W3);
  k_ih<<<1024, 256, 0, stream>>>(x, W3, b_ih_f, b_hh_f, b_ih_b, b_hh_b, PRE);
  k_rnn<<<1024, 512, 0, stream>>>(PRE, w_hh_f, w_hh_b);
  k_lin<<<256, 256, 0, stream>>>(PRE, w_lin, b_lin, EM);
  k_crf<<<256, 128, 0, stream>>>(EM, y, st, en, trans, PART, CNT, out);
}